// Round 6
// baseline (146.630 us; speedup 1.0000x reference)
//
#include <hip/hip_runtime.h>
#include <math.h>

#define NB 2
#define NH 8
#define BHN 16
#define SS 160
#define DD 64

typedef __attribute__((ext_vector_type(8))) short bf16x8;
typedef __attribute__((ext_vector_type(4))) float f32x4;

// split a pair of fp32 into packed bf16 (hi, lo); lo captures the residual.
__device__ __forceinline__ uint2 splitpair(float a0, float a1) {
    unsigned u0 = __float_as_uint(a0), u1 = __float_as_uint(a1);
    unsigned hi = (u0 >> 16) | (u1 & 0xffff0000u);
    float r0 = a0 - __uint_as_float(u0 & 0xffff0000u);
    float r1 = a1 - __uint_as_float(u1 & 0xffff0000u);
    unsigned v0 = __float_as_uint(r0), v1 = __float_as_uint(r1);
    unsigned lo = (v0 >> 16) | (v1 & 0xffff0000u);
    return make_uint2(hi, lo);
}

// zg: [16 bh][160 q][64 d] partial z sums; lg: [16 bh][160 q] exp-sums.
__global__ void zero_ws(float4* p) {
    int i = blockIdx.x * 256 + threadIdx.x;
    if (i < 41600) p[i] = make_float4(0.f, 0.f, 0.f, 0.f);
}

// ============================ PHASE 1 ============================
// Block = (bh, q-chunk 32, s-chunk 16). grid = 16*5*10 = 800 -> 3 blocks/CU.
// Per fixed s: scores[q32, t160] = (Q ⊙ k1[s,:]) x k2^T, 3-term bf16 hi/lo
// MFMA. All k2 fragments (hi AND lo) hoisted to registers; s-loop reads only
// k1 broadcasts from LDS. m=0 softmax (scores bounded ~45, exp fits fp32).
// Epilogue fuses both GEMVs: z_partial = A1(chunk)·v1 + A2(full t)·v2,
// atomicAdd into zg; l partial into lg. LDS 46 KB.
__global__ __launch_bounds__(256, 3) void tritt_p1(
    const float* __restrict__ q,  const float* __restrict__ k1,
    const float* __restrict__ k2, const float* __restrict__ v1,
    const float* __restrict__ v2, float* __restrict__ zg,
    float* __restrict__ lg)
{
    __shared__ __align__(16) char sm[47104];
    char*  k2hB  = sm;                       // bf16 hi [160 t][8 blk][16B]
    char*  k2lB  = sm + 20480;               // bf16 lo
    float* k1buf = (float*)(sm + 40960);     // [16 s][64 h]
    float* A1buf = (float*)(sm + 45056);     // [16 s][32 q]
    float* A2s   = (float*)sm;               // after s-loop: [32 q][164] f32

    const int tid = threadIdx.x;
    const int blk = blockIdx.x;
    const int bh  = blk / 50;
    const int rem = blk % 50;
    const int qc  = rem / 10, sc = rem % 10;
    const size_t base = (size_t)bh * SS * DD;

    // ---- stage k2 (all 160 t) as hi/lo bf16, 16B-block swizzled by t&7 ----
    const float4* k2f = (const float4*)(k2 + base);
    #pragma unroll
    for (int it = 0; it < 5; ++it) {
        int f = tid + 256 * it;          // t = f>>3, 16B-block o = f&7
        int t = f >> 3, o = f & 7;
        float4 x0 = k2f[t * 16 + 2 * o];
        float4 x1 = k2f[t * 16 + 2 * o + 1];
        uint2 p0 = splitpair(x0.x, x0.y);
        uint2 p1 = splitpair(x0.z, x0.w);
        uint2 p2 = splitpair(x1.x, x1.y);
        uint2 p3 = splitpair(x1.z, x1.w);
        int off = t * 128 + ((o ^ (t & 7)) * 16);
        *(uint4*)(k2hB + off) = make_uint4(p0.x, p1.x, p2.x, p3.x);
        *(uint4*)(k2lB + off) = make_uint4(p0.y, p1.y, p2.y, p3.y);
    }
    // ---- stage k1 chunk (16 rows, fp32) ----
    ((float4*)k1buf)[tid] = ((const float4*)(k1 + base))[sc * 256 + tid];
    if (tid < 128) ((float4*)A1buf)[tid] = make_float4(0.f, 0.f, 0.f, 0.f);

    const int lane = tid & 63, wid = tid >> 6;
    const int mt = wid & 1, nh = wid >> 1;
    const int n16 = lane & 15, quad = lane >> 4;

    // Q rows (fp32, registers): lane n16 -> q row, quad -> h-octet
    const float* qrow = q + base + (size_t)(qc * 32 + mt * 16 + n16) * DD + quad * 8;
    float Qf[2][8];
    #pragma unroll
    for (int ks = 0; ks < 2; ++ks) {
        float4 a = *(const float4*)(qrow + 32 * ks);
        float4 b = *(const float4*)(qrow + 32 * ks + 4);
        Qf[ks][0] = a.x; Qf[ks][1] = a.y; Qf[ks][2] = a.z; Qf[ks][3] = a.w;
        Qf[ks][4] = b.x; Qf[ks][5] = b.y; Qf[ks][6] = b.z; Qf[ks][7] = b.w;
    }
    __syncthreads();

    // ---- hoist ALL k2 fragments (hi+lo) into registers (s-invariant) ----
    const int trow = nh * 80 + n16;
    const int swz  = n16 & 7;
    const char* bb0 = k2hB + trow * 128 + ((quad) ^ swz) * 16;
    const char* bb1 = k2hB + trow * 128 + ((4 + quad) ^ swz) * 16;
    const char* lb0 = k2lB + trow * 128 + ((quad) ^ swz) * 16;
    const char* lb1 = k2lB + trow * 128 + ((4 + quad) ^ swz) * 16;
    bf16x8 BH0[5], BH1[5], BL0[5], BL1[5];
    #pragma unroll
    for (int j = 0; j < 5; ++j) {
        BH0[j] = *(const bf16x8*)(bb0 + 2048 * j);
        BH1[j] = *(const bf16x8*)(bb1 + 2048 * j);
        BL0[j] = *(const bf16x8*)(lb0 + 2048 * j);
        BL1[j] = *(const bf16x8*)(lb1 + 2048 * j);
    }

    f32x4 A2acc[5];
    #pragma unroll
    for (int j = 0; j < 5; ++j) A2acc[j] = (f32x4){0.f, 0.f, 0.f, 0.f};
    const f32x4 zero4 = (f32x4){0.f, 0.f, 0.f, 0.f};

    // ---- s-loop (16): build A = Q ⊙ k1[s,:], 30 MFMAs, exp, accumulate ----
    #pragma unroll 2
    for (int s = 0; s < 16; ++s) {
        const float* k1row = k1buf + s * 64 + quad * 8;
        uint4 AH[2], AL[2];
        #pragma unroll
        for (int ks = 0; ks < 2; ++ks) {
            float4 a = *(const float4*)(k1row + 32 * ks);
            float4 b = *(const float4*)(k1row + 32 * ks + 4);
            uint2 p0 = splitpair(Qf[ks][0] * a.x, Qf[ks][1] * a.y);
            uint2 p1 = splitpair(Qf[ks][2] * a.z, Qf[ks][3] * a.w);
            uint2 p2 = splitpair(Qf[ks][4] * b.x, Qf[ks][5] * b.y);
            uint2 p3 = splitpair(Qf[ks][6] * b.z, Qf[ks][7] * b.w);
            AH[ks] = make_uint4(p0.x, p1.x, p2.x, p3.x);
            AL[ks] = make_uint4(p0.y, p1.y, p2.y, p3.y);
        }
        bf16x8 ah0 = *(bf16x8*)&AH[0], al0 = *(bf16x8*)&AL[0];
        bf16x8 ah1 = *(bf16x8*)&AH[1], al1 = *(bf16x8*)&AL[1];

        float rsum[4] = {0.f, 0.f, 0.f, 0.f};
        #pragma unroll
        for (int j = 0; j < 5; ++j) {
            f32x4 a = __builtin_amdgcn_mfma_f32_16x16x32_bf16(ah0, BH0[j], zero4, 0, 0, 0);
            a = __builtin_amdgcn_mfma_f32_16x16x32_bf16(al0, BH0[j], a, 0, 0, 0);
            a = __builtin_amdgcn_mfma_f32_16x16x32_bf16(ah0, BL0[j], a, 0, 0, 0);
            a = __builtin_amdgcn_mfma_f32_16x16x32_bf16(ah1, BH1[j], a, 0, 0, 0);
            a = __builtin_amdgcn_mfma_f32_16x16x32_bf16(al1, BH1[j], a, 0, 0, 0);
            a = __builtin_amdgcn_mfma_f32_16x16x32_bf16(ah1, BL1[j], a, 0, 0, 0);
            #pragma unroll
            for (int r = 0; r < 4; ++r) {
                float e = __expf(a[r]);
                A2acc[j][r] += e;
                rsum[r] += e;
            }
        }
        #pragma unroll
        for (int r = 0; r < 4; ++r) {
            float v = rsum[r];
            v += __shfl_xor(v, 1, 64); v += __shfl_xor(v, 2, 64);
            v += __shfl_xor(v, 4, 64); v += __shfl_xor(v, 8, 64);
            if (n16 == 0)
                atomicAdd(&A1buf[s * 32 + mt * 16 + quad * 4 + r], v);
        }
    }
    __syncthreads();   // k2 LDS dead (frags in regs); A1buf final

    // ---- dump A2acc to LDS [32 q][stride 164] (2-way conflicts, free) ----
    {
        float* dst = A2s + (size_t)(mt * 16 + quad * 4) * 164 + nh * 80 + n16;
        #pragma unroll
        for (int j = 0; j < 5; ++j)
            #pragma unroll
            for (int r = 0; r < 4; ++r)
                dst[r * 164 + j * 16] = A2acc[j][r];
    }
    // ---- l partial from A1buf ----
    if (tid < 32) {
        float lq = 0.f;
        #pragma unroll
        for (int s = 0; s < 16; ++s) lq += A1buf[s * 32 + tid];
        atomicAdd(&lg[bh * SS + qc * 32 + tid], lq);
    }
    __syncthreads();

    // ---- fused GEMV: z[q, 4d] = A1·v1(chunk) + A2·v2(all t); 2 q/thread ----
    const int d4 = tid & 15, qq = tid >> 4;          // d = 4*d4; q_local = qq, qq+16
    f32x4 z0 = (f32x4){0.f, 0.f, 0.f, 0.f};
    f32x4 z1 = (f32x4){0.f, 0.f, 0.f, 0.f};
    const float4* v2f = (const float4*)(v2 + base);
    const float* a2r0 = A2s + qq * 164;
    const float* a2r1 = A2s + (qq + 16) * 164;
    #pragma unroll 2
    for (int t4 = 0; t4 < 40; ++t4) {
        f32x4 a0 = *(const f32x4*)(a2r0 + 4 * t4);   // 16B-aligned (164*4%16==0)
        f32x4 a1 = *(const f32x4*)(a2r1 + 4 * t4);
        #pragma unroll
        for (int tt = 0; tt < 4; ++tt) {
            float4 vv = v2f[(4 * t4 + tt) * 16 + d4];
            float w0 = a0[tt], w1 = a1[tt];
            z0[0] = fmaf(w0, vv.x, z0[0]); z0[1] = fmaf(w0, vv.y, z0[1]);
            z0[2] = fmaf(w0, vv.z, z0[2]); z0[3] = fmaf(w0, vv.w, z0[3]);
            z1[0] = fmaf(w1, vv.x, z1[0]); z1[1] = fmaf(w1, vv.y, z1[1]);
            z1[2] = fmaf(w1, vv.z, z1[2]); z1[3] = fmaf(w1, vv.w, z1[3]);
        }
    }
    const float4* v1f = (const float4*)(v1 + base) + sc * 256;
    #pragma unroll
    for (int s = 0; s < 16; ++s) {
        float4 vv = v1f[s * 16 + d4];
        float w0 = A1buf[s * 32 + qq];
        float w1 = A1buf[s * 32 + qq + 16];
        z0[0] = fmaf(w0, vv.x, z0[0]); z0[1] = fmaf(w0, vv.y, z0[1]);
        z0[2] = fmaf(w0, vv.z, z0[2]); z0[3] = fmaf(w0, vv.w, z0[3]);
        z1[0] = fmaf(w1, vv.x, z1[0]); z1[1] = fmaf(w1, vv.y, z1[1]);
        z1[2] = fmaf(w1, vv.z, z1[2]); z1[3] = fmaf(w1, vv.w, z1[3]);
    }
    float* zp0 = zg + ((size_t)bh * SS + qc * 32 + qq) * DD + 4 * d4;
    float* zp1 = zp0 + 16 * DD;
    #pragma unroll
    for (int r = 0; r < 4; ++r) {
        atomicAdd(zp0 + r, z0[r]);
        atomicAdd(zp1 + r, z1[r]);
    }
}

// ============================ PHASE 3 ============================
__global__ void tritt_p3(const float* __restrict__ zg,
                         const float* __restrict__ lg, float* __restrict__ out)
{
    int i = blockIdx.x * 256 + threadIdx.x;          // < 163840
    out[i] = zg[i] / lg[i >> 6];
    if (i < BHN * SS) out[BHN * SS * DD + i] = __logf(lg[i]);
}

// ==================== FALLBACK (proven R2, ~74us) ====================
__global__ __launch_bounds__(256, 2) void tritt_fb(
    const float* __restrict__ q,  const float* __restrict__ k1,
    const float* __restrict__ k2, const float* __restrict__ v1,
    const float* __restrict__ v2, float* __restrict__ out)
{
    __shared__ __align__(16) char sm[81920];
    const int tid = threadIdx.x;
    const int blk = blockIdx.x;
    const int bh  = blk / SS;
    const int qi  = blk % SS;
    const size_t base = (size_t)bh * SS * DD;

    const float4* k1f = (const float4*)(k1 + base);
    const float4* k2f = (const float4*)(k2 + base);
    const float4* qf  = (const float4*)(q + base + (size_t)qi * DD);

    #pragma unroll
    for (int it = 0; it < 5; ++it) {
        int f = tid + 256 * it;
        int s = f >> 3, g = f & 7;
        int fg = s * 16 + g * 2;
        float4 x0 = k1f[fg], x1 = k1f[fg + 1];
        float4 y0 = k2f[fg], y1 = k2f[fg + 1];
        float4 q0 = qf[g * 2], q1 = qf[g * 2 + 1];
        uint2 pa0 = splitpair(x0.x * q0.x, x0.y * q0.y);
        uint2 pa1 = splitpair(x0.z * q0.z, x0.w * q0.w);
        uint2 pa2 = splitpair(x1.x * q1.x, x1.y * q1.y);
        uint2 pa3 = splitpair(x1.z * q1.z, x1.w * q1.w);
        uint2 pb0 = splitpair(y0.x, y0.y);
        uint2 pb1 = splitpair(y0.z, y0.w);
        uint2 pb2 = splitpair(y1.x, y1.y);
        uint2 pb3 = splitpair(y1.z, y1.w);
        int off = s * 128 + ((g ^ (s & 7)) * 16);
        *(uint4*)(sm + off)         = make_uint4(pa0.x, pa1.x, pa2.x, pa3.x);
        *(uint4*)(sm + 20480 + off) = make_uint4(pa0.y, pa1.y, pa2.y, pa3.y);
        *(uint4*)(sm + 40960 + off) = make_uint4(pb0.x, pb1.x, pb2.x, pb3.x);
        *(uint4*)(sm + 61440 + off) = make_uint4(pb0.y, pb1.y, pb2.y, pb3.y);
    }
    __syncthreads();

    const int lane = tid & 63;
    const int wid  = tid >> 6;
    const int wy = wid >> 1, wx = wid & 1;
    const int s0 = 80 * wy, t0 = 80 * wx;
    const int n16 = lane & 15, quad = lane >> 4, l7 = lane & 7;

    f32x4 acc[5][5];
    #pragma unroll
    for (int i = 0; i < 5; ++i)
        #pragma unroll
        for (int j = 0; j < 5; ++j) acc[i][j] = (f32x4){0.f, 0.f, 0.f, 0.f};

    #pragma unroll 1
    for (int ks = 0; ks < 2; ++ks) {
        const int sg = (4 * ks + quad) ^ l7;
        const char* abase = sm + (s0 + n16) * 128 + sg * 16;
        const char* bbase = sm + 40960 + (t0 + n16) * 128 + sg * 16;
        bf16x8 ah[5], al[5];
        #pragma unroll
        for (int i = 0; i < 5; ++i) {
            ah[i] = *(const bf16x8*)(abase + 2048 * i);
            al[i] = *(const bf16x8*)(abase + 20480 + 2048 * i);
        }
        #pragma unroll
        for (int j = 0; j < 5; ++j) {
            bf16x8 bh8 = *(const bf16x8*)(bbase + 2048 * j);
            bf16x8 bl8 = *(const bf16x8*)(bbase + 20480 + 2048 * j);
            #pragma unroll
            for (int i = 0; i < 5; ++i) {
                acc[i][j] = __builtin_amdgcn_mfma_f32_16x16x32_bf16(ah[i], bh8, acc[i][j], 0, 0, 0);
                acc[i][j] = __builtin_amdgcn_mfma_f32_16x16x32_bf16(al[i], bh8, acc[i][j], 0, 0, 0);
                acc[i][j] = __builtin_amdgcn_mfma_f32_16x16x32_bf16(ah[i], bl8, acc[i][j], 0, 0, 0);
            }
        }
    }
    __syncthreads();

    float* A1   = (float*)sm;
    float* A2   = A1 + SS;
    float* wred = A2 + SS;
    float* zred = wred + 8;

    if (tid < SS) { A1[tid] = 0.f; A2[tid] = 0.f; }

    float mloc = -1e30f;
    #pragma unroll
    for (int i = 0; i < 5; ++i)
        #pragma unroll
        for (int j = 0; j < 5; ++j)
            #pragma unroll
            for (int r = 0; r < 4; ++r) mloc = fmaxf(mloc, acc[i][j][r]);
    #pragma unroll
    for (int off = 32; off; off >>= 1) mloc = fmaxf(mloc, __shfl_xor(mloc, off, 64));
    if (lane == 0) wred[wid] = mloc;
    __syncthreads();
    const float m = fmaxf(fmaxf(wred[0], wred[1]), fmaxf(wred[2], wred[3]));

    float lsum = 0.f;
    #pragma unroll
    for (int i = 0; i < 5; ++i)
        #pragma unroll
        for (int j = 0; j < 5; ++j)
            #pragma unroll
            for (int r = 0; r < 4; ++r) {
                float e = __expf(acc[i][j][r] - m);
                acc[i][j][r] = e;
                lsum += e;
            }
    #pragma unroll
    for (int off = 32; off; off >>= 1) lsum += __shfl_xor(lsum, off, 64);
    if (lane == 0) wred[4 + wid] = lsum;

    #pragma unroll
    for (int i = 0; i < 5; ++i)
        #pragma unroll
        for (int r = 0; r < 4; ++r) {
            float rsv = 0.f;
            #pragma unroll
            for (int j = 0; j < 5; ++j) rsv += acc[i][j][r];
            rsv += __shfl_xor(rsv, 1, 64); rsv += __shfl_xor(rsv, 2, 64);
            rsv += __shfl_xor(rsv, 4, 64); rsv += __shfl_xor(rsv, 8, 64);
            if (n16 == 0) atomicAdd(&A1[s0 + 16 * i + 4 * quad + r], rsv);
        }
    #pragma unroll
    for (int j = 0; j < 5; ++j) {
        float csv = 0.f;
        #pragma unroll
        for (int i = 0; i < 5; ++i)
            #pragma unroll
            for (int r = 0; r < 4; ++r) csv += acc[i][j][r];
        csv += __shfl_xor(csv, 16, 64);
        csv += __shfl_xor(csv, 32, 64);
        if (quad == 0) atomicAdd(&A2[t0 + 16 * j + n16], csv);
    }
    __syncthreads();

    const float l = (wred[4] + wred[5]) + (wred[6] + wred[7]);
    if (tid == 0)
        out[(size_t)NB * NH * SS * DD + (size_t)bh * SS + qi] = m + __logf(l);

    const int d    = tid & 63;
    const int part = tid >> 6;
    const float* v1p = v1 + base;
    const float* v2p = v2 + base;
    float z = 0.f;
    #pragma unroll 4
    for (int s = part * 40; s < part * 40 + 40; ++s)
        z = fmaf(A1[s], v1p[s * DD + d], fmaf(A2[s], v2p[s * DD + d], z));
    zred[tid] = z;
    __syncthreads();
    if (tid < DD) {
        float zz = (zred[tid] + zred[tid + 64]) + (zred[tid + 128] + zred[tid + 192]);
        out[((size_t)bh * SS + qi) * DD + tid] = zz / l;
    }
}

extern "C" void kernel_launch(void* const* d_in, const int* in_sizes, int n_in,
                              void* d_out, int out_size, void* d_ws, size_t ws_size,
                              hipStream_t stream) {
    const float* q  = (const float*)d_in[0];
    const float* k1 = (const float*)d_in[1];
    const float* k2 = (const float*)d_in[2];
    const float* v1 = (const float*)d_in[3];
    const float* v2 = (const float*)d_in[4];
    float* out = (float*)d_out;

    const size_t REQ = (size_t)(BHN * SS * DD + BHN * SS) * sizeof(float); // 666 KB
    if (ws_size >= REQ) {
        float* zg = (float*)d_ws;                // 163840 floats
        float* lg = zg + BHN * SS * DD;          // 2560 floats
        zero_ws<<<dim3(163), dim3(256), 0, stream>>>((float4*)d_ws);
        tritt_p1<<<dim3(800), dim3(256), 0, stream>>>(q, k1, k2, v1, v2, zg, lg);
        tritt_p3<<<dim3(640), dim3(256), 0, stream>>>(zg, lg, out);
    } else {
        tritt_fb<<<dim3(NB * NH * SS), dim3(256), 0, stream>>>(q, k1, k2, v1, v2, out);
    }
}